// Round 9
// baseline (151.677 us; speedup 1.0000x reference)
//
#include <hip/hip_runtime.h>

#define B_ 2
#define H_ 16
#define N_ 2048
#define D_ 64
#define NH_ (B_*H_)            // 32 heads
#define ROWS_ (NH_*N_)         // 65536 rows per tensor
#define KVB 64
#define NT (N_/KVB)            // 32 kv tiles
#define LOG2E 1.4426950408889634f
#define QSCALE (0.25f * LOG2E)

typedef _Float16 f16;
typedef _Float16 f16x2 __attribute__((ext_vector_type(2)));
typedef _Float16 f16x4 __attribute__((ext_vector_type(4)));
typedef _Float16 f16x8 __attribute__((ext_vector_type(8)));
typedef __fp16 h16x2 __attribute__((ext_vector_type(2)));
typedef float f32x4 __attribute__((ext_vector_type(4)));

typedef __attribute__((address_space(1))) const void g_void;
typedef __attribute__((address_space(3))) void l_void;

__device__ __forceinline__ void gl_lds16(const void* g, void* l) {
  __builtin_amdgcn_global_load_lds((g_void*)g, (l_void*)l, 16, 0, 0);
}

__device__ __forceinline__ f16x2 cvt_pk(float a, float b) {
  return __builtin_bit_cast(f16x2, __builtin_amdgcn_cvt_pkrtz(a, b));
}

__device__ __forceinline__ float dot2acc(f16x2 a, f16x2 b, float c) {
#if __has_builtin(__builtin_amdgcn_fdot2)
  return __builtin_amdgcn_fdot2(__builtin_bit_cast(h16x2, a),
                                __builtin_bit_cast(h16x2, b), c, false);
#else
  return c + (float)a[0] * (float)b[0] + (float)a[1] * (float)b[1];
#endif
}

// ---------------------------------------------------------------------------
// Prep: blocks [0,1024): V^T via in-register 4x4 transpose (no LDS).
//       blocks [1024,2048): q,k f32->f16 (+bias) grid-stride, 8 lanes/row.
// qh = f16(0.25*log2e * q); bias = masked ? -1e30 : -|k|^2 * log2e
// ---------------------------------------------------------------------------
__global__ __launch_bounds__(256) void prep_all(
    const float* __restrict__ q, const float* __restrict__ k,
    const float* __restrict__ v, const void* __restrict__ mask,
    f16* __restrict__ qh, f16* __restrict__ kh, f16* __restrict__ vt,
    float* __restrict__ bias) {
  int tid = threadIdx.x;
  if (blockIdx.x < 1024) {
    int head = blockIdx.x >> 5;
    int n0 = (blockIdx.x & 31) << 6;
    int e = tid & 15, gq = tid >> 4;
    const float* src = v + ((long)head * N_ + n0 + e * 4) * D_ + gq * 4;
    f32x4 r0 = *(const f32x4*)(src);
    f32x4 r1 = *(const f32x4*)(src + D_);
    f32x4 r2 = *(const f32x4*)(src + 2 * D_);
    f32x4 r3 = *(const f32x4*)(src + 3 * D_);
    f16* dst = vt + (long)head * D_ * N_ + n0 + e * 4;
#pragma unroll
    for (int c = 0; c < 4; ++c) {
      f16x4 y;
      y[0] = (f16)r0[c]; y[1] = (f16)r1[c]; y[2] = (f16)r2[c]; y[3] = (f16)r3[c];
      *(f16x4*)(dst + (long)(gq * 4 + c) * N_) = y;
    }
  } else {
    int wid = (blockIdx.x - 1024) * 4 + (tid >> 6);
    int lane = tid & 63;
    int r8 = lane >> 3, e = lane & 7;
    const unsigned* mw = (const unsigned*)mask;
    bool bytes_mode = __any(mw[lane] > 1u);
#pragma unroll
    for (int trip = 0; trip < 4; ++trip) {
      long grow = ((long)(trip * 4096 + wid)) * 8 + r8;
      bool isK = grow >= ROWS_;
      long row = isK ? grow - ROWS_ : grow;
      const float* s = (isK ? k : q) + row * D_ + e * 8;
      f32x4 x0 = *(const f32x4*)s;
      f32x4 x1 = *(const f32x4*)(s + 4);
      float scl = isK ? 1.0f : QSCALE;
      f16x8 hv;
#pragma unroll
      for (int c = 0; c < 4; ++c) { hv[c] = (f16)(x0[c] * scl); hv[4 + c] = (f16)(x1[c] * scl); }
      *(f16x8*)((isK ? kh : qh) + row * D_ + e * 8) = hv;
      if (isK) {
        float sq = x0[0]*x0[0] + x0[1]*x0[1] + x0[2]*x0[2] + x0[3]*x0[3]
                 + x1[0]*x1[0] + x1[1]*x1[1] + x1[2]*x1[2] + x1[3]*x1[3];
        sq += __shfl_xor(sq, 1); sq += __shfl_xor(sq, 2); sq += __shfl_xor(sq, 4);
        if (e == 0) {
          int b = (int)(row >> 15);
          int n = (int)(row & (N_ - 1));
          int mv = bytes_mode ? (int)((const unsigned char*)mask)[b * N_ + n]
                              : ((const int*)mask)[b * N_ + n];
          bias[row] = mv ? -1e30f : -sq * LOG2E;
        }
      }
    }
  }
}

// ---------------------------------------------------------------------------
// Main: flash attention. 2 waves/block, 32 q-rows/wave (two 16-row tiles A,B)
// so each K/V LDS fragment read feeds 4 MFMAs (2x amortization; LDS-BW was
// the measured floor at R8). Swapped-operand QK^T with (bias - m) as C-in;
// per-lane fast-path (no cross-lane ops); l-reduce at epilogue; iter 0 peeled.
// LDS 40KB -> 4 blk/CU (8 waves/CU).
// ---------------------------------------------------------------------------
__global__ __launch_bounds__(128, 2) void attend_main(
    const f16* __restrict__ qh, const f16* __restrict__ kh,
    const f16* __restrict__ vt, const float* __restrict__ bias,
    float* __restrict__ out) {
  __shared__ f16 Kt[2][4096];      // 16 KiB
  __shared__ f16 Vt[2][4096];      // 16 KiB
  __shared__ f16 Pb[2][2][1024];   // 8 KiB: [wave][qtile][16q x 64k]

  int tid = threadIdx.x;
  int w = tid >> 6, lane = tid & 63;
  int j = lane & 15, g = lane >> 4;

  int bid = (blockIdx.x & 7) * 128 + (blockIdx.x >> 3);
  int head = bid >> 5;
  int qt = bid & 31;
  int qrow0 = qt * 64 + w * 32;            // wave owns rows [qrow0, qrow0+32)
  int off = ((bid >> 5) & 3) * 8;

  const f16* qbase = qh + ((long)head * N_ + qrow0 + j) * D_;
  f16x8 qfA0 = *(const f16x8*)(qbase + g * 8);
  f16x8 qfA1 = *(const f16x8*)(qbase + 32 + g * 8);
  f16x8 qfB0 = *(const f16x8*)(qbase + 16 * D_ + g * 8);
  f16x8 qfB1 = *(const f16x8*)(qbase + 16 * D_ + 32 + g * 8);

  const char* kg = (const char*)(kh + (long)head * N_ * D_);
  const char* vg = (const char*)(vt + (long)head * D_ * N_);
  const float* bb = bias + (long)head * N_ + g * 4;

  int ko0[4], ko1[4];
#pragma unroll
  for (int x = 0; x < 4; ++x) {
    int rk = x * 16 + j;
    int swk = (rk & 7) << 4;
    ko0[x] = ((rk << 7) + g * 16) ^ swk;
    ko1[x] = ((rk << 7) + 64 + g * 16) ^ swk;
  }
  int pswz = (j & 7) << 4;
  int pw0 = ((j << 7) + g * 8) ^ pswz;
  int pr0 = ((j << 7) + g * 16) ^ pswz;
  int pr1 = ((j << 7) + 64 + g * 16) ^ pswz;

  f32x4 OA0 = {0,0,0,0}, OA1 = {0,0,0,0}, OA2 = {0,0,0,0}, OA3 = {0,0,0,0};
  f32x4 OB0 = {0,0,0,0}, OB1 = {0,0,0,0}, OB2 = {0,0,0,0}, OB3 = {0,0,0,0};
  float mA = -1e30f, lA = 0.f, mB = -1e30f, lB = 0.f;

  auto stage = [&](int buf, int t) {
    int kv = t * KVB;
    if (w == 0) {                     // K tile: 8KB contiguous
      const char* src = kg + (size_t)kv * 128;
      char* lb = (char*)&Kt[buf][0];
#pragma unroll
      for (int c = 0; c < 8; ++c) {
        int o = c * 1024 + lane * 16;
        int p = o ^ (((o >> 7) & 7) << 4);
        gl_lds16(src + p, lb + c * 1024);
      }
    } else {                          // V^T tile: 64 rows of 128B, stride N_*2
      const char* src = vg + (size_t)kv * 2;
      char* lb = (char*)&Vt[buf][0];
#pragma unroll
      for (int c = 0; c < 8; ++c) {
        int o = c * 1024 + lane * 16;
        int p = o ^ (((o >> 7) & 7) << 4);
        gl_lds16(src + (size_t)(p >> 7) * (N_ * 2) + (p & 127), lb + c * 1024);
      }
    }
  };

  auto qkt2 = [&](const char* Kc, f32x4* sA, f32x4* sB,
                  const f32x4* cinA, const f32x4* cinB) {
    __builtin_amdgcn_s_setprio(1);
#pragma unroll
    for (int jt = 0; jt < 4; ++jt) {
      f16x8 k0 = *(const f16x8*)(Kc + ko0[jt]);
      f16x8 k1 = *(const f16x8*)(Kc + ko1[jt]);
      f32x4 a = __builtin_amdgcn_mfma_f32_16x16x32_f16(k0, qfA0, cinA[jt], 0, 0, 0);
      f32x4 b = __builtin_amdgcn_mfma_f32_16x16x32_f16(k0, qfB0, cinB[jt], 0, 0, 0);
      sA[jt]  = __builtin_amdgcn_mfma_f32_16x16x32_f16(k1, qfA1, a, 0, 0, 0);
      sB[jt]  = __builtin_amdgcn_mfma_f32_16x16x32_f16(k1, qfB1, b, 0, 0, 0);
    }
    __builtin_amdgcn_s_setprio(0);
  };

  auto finish_pv2 = [&](const char* Vc, const f32x4* sA, const f32x4* sB) {
    f16x2 pkA[8], pkB[8];
    float rsA = 0.f, rsB = 0.f;
    const f16x2 ones = {(f16)1.0f, (f16)1.0f};
#pragma unroll
    for (int jt = 0; jt < 4; ++jt) {
      float a0 = __builtin_amdgcn_exp2f(sA[jt][0]);
      float a1 = __builtin_amdgcn_exp2f(sA[jt][1]);
      float a2 = __builtin_amdgcn_exp2f(sA[jt][2]);
      float a3 = __builtin_amdgcn_exp2f(sA[jt][3]);
      float b0 = __builtin_amdgcn_exp2f(sB[jt][0]);
      float b1 = __builtin_amdgcn_exp2f(sB[jt][1]);
      float b2 = __builtin_amdgcn_exp2f(sB[jt][2]);
      float b3 = __builtin_amdgcn_exp2f(sB[jt][3]);
      pkA[jt*2+0] = cvt_pk(a0, a1); pkA[jt*2+1] = cvt_pk(a2, a3);
      pkB[jt*2+0] = cvt_pk(b0, b1); pkB[jt*2+1] = cvt_pk(b2, b3);
      rsA = dot2acc(pkA[jt*2+0], ones, rsA); rsA = dot2acc(pkA[jt*2+1], ones, rsA);
      rsB = dot2acc(pkB[jt*2+0], ones, rsB); rsB = dot2acc(pkB[jt*2+1], ones, rsB);
    }
    lA += rsA; lB += rsB;
    char* PwA = (char*)&Pb[w][0][0];
    char* PwB = (char*)&Pb[w][1][0];
#pragma unroll
    for (int jt = 0; jt < 4; ++jt) {
      f16x4 pa = __builtin_shufflevector(pkA[jt*2], pkA[jt*2+1], 0, 1, 2, 3);
      f16x4 pb = __builtin_shufflevector(pkB[jt*2], pkB[jt*2+1], 0, 1, 2, 3);
      *(f16x4*)(PwA + (pw0 ^ (jt * 32))) = pa;
      *(f16x4*)(PwB + (pw0 ^ (jt * 32))) = pb;
    }
    f16x8 pfA0 = *(const f16x8*)(PwA + pr0);
    f16x8 pfA1 = *(const f16x8*)(PwA + pr1);
    f16x8 pfB0 = *(const f16x8*)(PwB + pr0);
    f16x8 pfB1 = *(const f16x8*)(PwB + pr1);
    __builtin_amdgcn_s_setprio(1);
#pragma unroll
    for (int dt = 0; dt < 4; ++dt) {
      f16x8 v0 = *(const f16x8*)(Vc + ko0[dt]);
      f16x8 v1 = *(const f16x8*)(Vc + ko1[dt]);
      f32x4* OdA = (dt == 0) ? &OA0 : (dt == 1) ? &OA1 : (dt == 2) ? &OA2 : &OA3;
      f32x4* OdB = (dt == 0) ? &OB0 : (dt == 1) ? &OB1 : (dt == 2) ? &OB2 : &OB3;
      *OdA = __builtin_amdgcn_mfma_f32_16x16x32_f16(pfA0, v0, *OdA, 0, 0, 0);
      *OdB = __builtin_amdgcn_mfma_f32_16x16x32_f16(pfB0, v0, *OdB, 0, 0, 0);
      *OdA = __builtin_amdgcn_mfma_f32_16x16x32_f16(pfA1, v1, *OdA, 0, 0, 0);
      *OdB = __builtin_amdgcn_mfma_f32_16x16x32_f16(pfB1, v1, *OdB, 0, 0, 0);
    }
    __builtin_amdgcn_s_setprio(0);
  };

  auto lane_max16 = [&](const f32x4* s) {
    float a0 = fmaxf(fmaxf(s[0][0], s[0][1]), fmaxf(s[0][2], s[0][3]));
    float a1 = fmaxf(fmaxf(s[1][0], s[1][1]), fmaxf(s[1][2], s[1][3]));
    float a2 = fmaxf(fmaxf(s[2][0], s[2][1]), fmaxf(s[2][2], s[2][3]));
    float a3 = fmaxf(fmaxf(s[3][0], s[3][1]), fmaxf(s[3][2], s[3][3]));
    return fmaxf(fmaxf(a0, a1), fmaxf(a2, a3));
  };

  f32x4 bnx[4];                      // bias of CURRENT tile (shared by A,B)
#pragma unroll
  for (int jt = 0; jt < 4; ++jt) bnx[jt] = *(const f32x4*)(bb + off * KVB + jt * 16);

  stage(0, off);
  __syncthreads();
  int cur = 0;

  // ---- peeled iteration 0: establish mA/mB on the real scale ----
  {
    int tn = (off + 1) & (NT - 1);
    stage(1, tn);
    f32x4 sA[4], sB[4];
    qkt2((const char*)&Kt[0][0], sA, sB, bnx, bnx);
#pragma unroll
    for (int jt = 0; jt < 4; ++jt) bnx[jt] = *(const f32x4*)(bb + tn * KVB + jt * 16);

    float ta = lane_max16(sA), tb = lane_max16(sB);
    ta = fmaxf(ta, __shfl_xor(ta, 16)); ta = fmaxf(ta, __shfl_xor(ta, 32));
    tb = fmaxf(tb, __shfl_xor(tb, 16)); tb = fmaxf(tb, __shfl_xor(tb, 32));
    mA = ta; mB = tb;
#pragma unroll
    for (int jt = 0; jt < 4; ++jt)
#pragma unroll
      for (int r = 0; r < 4; ++r) { sA[jt][r] -= mA; sB[jt][r] -= mB; }
    finish_pv2((const char*)&Vt[0][0], sA, sB);
    __syncthreads();
    cur = 1;
  }

  for (int t = 1; t < NT; ++t) {
    int tt = (t + off) & (NT - 1);
    int tn = (tt + 1) & (NT - 1);

    f32x4 madjA[4], madjB[4];
#pragma unroll
    for (int jt = 0; jt < 4; ++jt) {
#pragma unroll
      for (int r = 0; r < 4; ++r) {
        madjA[jt][r] = bnx[jt][r] - mA;
        madjB[jt][r] = bnx[jt][r] - mB;
      }
    }
    if (t + 1 < NT) stage(cur ^ 1, tn);

    f32x4 sA[4], sB[4];
    qkt2((const char*)&Kt[cur][0], sA, sB, madjA, madjB);

    if (t + 1 < NT) {
#pragma unroll
      for (int jt = 0; jt < 4; ++jt)
        bnx[jt] = *(const f32x4*)(bb + tn * KVB + jt * 16);
    }

    float tLA = lane_max16(sA);
    float tLB = lane_max16(sB);
    if (!__all(fmaxf(tLA, tLB) <= 8.0f)) {
      float ta = fmaxf(tLA, __shfl_xor(tLA, 16));
      ta = fmaxf(ta, __shfl_xor(ta, 32));
      float tb = fmaxf(tLB, __shfl_xor(tLB, 16));
      tb = fmaxf(tb, __shfl_xor(tb, 32));
      float dA = fmaxf(ta, 0.0f), dB = fmaxf(tb, 0.0f);
      float scA = __builtin_amdgcn_exp2f(-dA);
      float scB = __builtin_amdgcn_exp2f(-dB);
      mA += dA; mB += dB;
      lA *= scA; lB *= scB;
#pragma unroll
      for (int r = 0; r < 4; ++r) {
        float sa = __shfl(scA, g * 4 + r);
        float sb = __shfl(scB, g * 4 + r);
        OA0[r] *= sa; OA1[r] *= sa; OA2[r] *= sa; OA3[r] *= sa;
        OB0[r] *= sb; OB1[r] *= sb; OB2[r] *= sb; OB3[r] *= sb;
      }
#pragma unroll
      for (int jt = 0; jt < 4; ++jt)
#pragma unroll
        for (int r = 0; r < 4; ++r) { sA[jt][r] -= dA; sB[jt][r] -= dB; }
    }

    finish_pv2((const char*)&Vt[cur][0], sA, sB);
    __syncthreads();
    cur ^= 1;
  }

  // ---- epilogue ----
  lA += __shfl_xor(lA, 16); lA += __shfl_xor(lA, 32);
  lB += __shfl_xor(lB, 16); lB += __shfl_xor(lB, 32);
  float* ob = out + ((long)head * N_ + qrow0 + g * 4) * D_ + j;
#pragma unroll
  for (int r = 0; r < 4; ++r) {
    float invA = 1.0f / __shfl(lA, g * 4 + r);
    float invB = 1.0f / __shfl(lB, g * 4 + r);
    float* oa = ob + (long)r * D_;
    float* obp = ob + (long)(16 + r) * D_;
    oa[0]  = OA0[r] * invA; oa[16] = OA1[r] * invA;
    oa[32] = OA2[r] * invA; oa[48] = OA3[r] * invA;
    obp[0]  = OB0[r] * invB; obp[16] = OB1[r] * invB;
    obp[32] = OB2[r] * invB; obp[48] = OB3[r] * invB;
  }
}

extern "C" void kernel_launch(void* const* d_in, const int* in_sizes, int n_in,
                              void* d_out, int out_size, void* d_ws, size_t ws_size,
                              hipStream_t stream) {
  const float* q = (const float*)d_in[0];
  const float* k = (const float*)d_in[1];
  const float* v = (const float*)d_in[2];
  const void* mask = d_in[3];

  char* ws = (char*)d_ws;
  f16*   qh   = (f16*)ws;
  f16*   kh   = (f16*)(ws + (8u  << 20));
  f16*   vt   = (f16*)(ws + (16u << 20));
  float* bias = (float*)(ws + (24u << 20));
  float* out  = (float*)d_out;

  prep_all<<<dim3(2048), dim3(256), 0, stream>>>(q, k, v, mask, qh, kh, vt, bias);
  attend_main<<<dim3(NH_ * (N_ / 64)), dim3(128), 0, stream>>>(qh, kh, vt, bias, out);
}